// Round 4
// baseline (347.408 us; speedup 1.0000x reference)
//
#include <hip/hip_runtime.h>
#include <hip/hip_bf16.h>
#include <math.h>

#define N_NODES 100000
#define F_IN    128
#define HC      128      // H*C
#define NH      4
#define SLOPE   0.2f

#define NB      196      // buckets = ceil(N/512)
#define BSH     9        // bucket = dst >> 9, local = dst & 511
#define CAP     10240    // per-bucket arena capacity (mean 8163, sigma ~90)
#define CHUNK   4096     // edges per k_bucket block

static __device__ __forceinline__ float leaky(float x) { return x > 0.f ? x : SLOPE * x; }

static __device__ __forceinline__ unsigned short f2b(float f) {
    __hip_bfloat16 b = __float2bfloat16(f);   // RTN-even
    return *reinterpret_cast<unsigned short*>(&b);
}

// ---------------------------------------------------------------------------
// K1: h = x @ W (100000x128 @ 128x128, fp32 compute). BM=64/block, 8x4/thread.
// h stored ONLY as bf16 (halves gather traffic downstream; fp32 h never hits
// memory). a_src/a_dst computed from fp32 accumulators in the epilogue.
// ---------------------------------------------------------------------------
__global__ __launch_bounds__(256) void k_gemm(const float* __restrict__ x,
                                              const float* __restrict__ W,
                                              const float* __restrict__ att_src,
                                              const float* __restrict__ att_dst,
                                              unsigned short* __restrict__ hb,
                                              float* __restrict__ a_src,
                                              float* __restrict__ a_dst)
{
    __shared__ float xs[128 * 66];
    const int t  = threadIdx.x;
    const int r0 = blockIdx.x * 64;

    for (int i = t; i < 2048; i += 256) {
        int row = i >> 5, kq = i & 31;
        int gr = r0 + row;
        float4 v = make_float4(0.f, 0.f, 0.f, 0.f);
        if (gr < N_NODES) v = ((const float4*)(x + (size_t)gr * F_IN))[kq];
        xs[(4 * kq + 0) * 66 + row] = v.x;
        xs[(4 * kq + 1) * 66 + row] = v.y;
        xs[(4 * kq + 2) * 66 + row] = v.z;
        xs[(4 * kq + 3) * 66 + row] = v.w;
    }
    __syncthreads();

    const int cg = t & 31;
    const int rg = t >> 5;

    float acc[8][4];
    #pragma unroll
    for (int r = 0; r < 8; ++r)
        for (int c = 0; c < 4; ++c) acc[r][c] = 0.f;

    #pragma unroll 4
    for (int k = 0; k < 128; ++k) {
        float4 wv = *(const float4*)&W[k * HC + 4 * cg];
        #pragma unroll
        for (int r = 0; r < 8; ++r) {
            float xv = xs[k * 66 + rg * 8 + r];
            acc[r][0] += xv * wv.x;
            acc[r][1] += xv * wv.y;
            acc[r][2] += xv * wv.z;
            acc[r][3] += xv * wv.w;
        }
    }

    #pragma unroll
    for (int r = 0; r < 8; ++r) {
        int gr = r0 + rg * 8 + r;
        if (gr < N_NODES) {
            ushort4 hv;
            hv.x = f2b(acc[r][0]); hv.y = f2b(acc[r][1]);
            hv.z = f2b(acc[r][2]); hv.w = f2b(acc[r][3]);
            *(ushort4*)&hb[(size_t)gr * HC + 4 * cg] = hv;
        }
    }

    const int head = cg >> 3;
    const float4 atts = *(const float4*)&att_src[head * 32 + (cg & 7) * 4];
    const float4 attd = *(const float4*)&att_dst[head * 32 + (cg & 7) * 4];
    #pragma unroll
    for (int r = 0; r < 8; ++r) {
        float ps = acc[r][0] * atts.x + acc[r][1] * atts.y +
                   acc[r][2] * atts.z + acc[r][3] * atts.w;
        float pd = acc[r][0] * attd.x + acc[r][1] * attd.y +
                   acc[r][2] * attd.z + acc[r][3] * attd.w;
        ps += __shfl_xor(ps, 1); pd += __shfl_xor(pd, 1);
        ps += __shfl_xor(ps, 2); pd += __shfl_xor(pd, 2);
        ps += __shfl_xor(ps, 4); pd += __shfl_xor(pd, 4);
        int gr = r0 + rg * 8 + r;
        if ((cg & 7) == 0 && gr < N_NODES) {
            a_src[gr * NH + head] = ps;
            a_dst[gr * NH + head] = pd;
        }
    }
}

// ---------------------------------------------------------------------------
// K2: multisplit edges into NB dst-buckets via LDS staging; dense flushes.
// Fused global degree histogram (fire-and-forget atomics). dst staged in LDS
// so global dstp is read exactly once. Self-loops never bucketed.
// ---------------------------------------------------------------------------
__global__ __launch_bounds__(256) void k_bucket(const int* __restrict__ srcp,
                                                const int* __restrict__ dstp,
                                                int* __restrict__ bucket_cursor,
                                                int* __restrict__ deg,
                                                int* __restrict__ eb, int E)
{
    __shared__ int dbuf[CHUNK];
    __shared__ int ebuf[CHUNK];
    __shared__ unsigned char bkt[CHUNK];
    __shared__ int hist[256];
    __shared__ int lexcl[257];
    __shared__ int gbase[256];
    __shared__ int sdata[256];

    const int t = threadIdx.x;
    const int base = blockIdx.x * CHUNK;

    hist[t] = 0;
    __syncthreads();

    // pass 1: histogram + stage dst
    #pragma unroll
    for (int j = 0; j < CHUNK / 256; ++j) {
        int i = base + t + j * 256;
        int d = (i < E) ? dstp[i] : -1;
        dbuf[t + j * 256] = d;
        if (i < E) atomicAdd(&hist[d >> BSH], 1);
    }
    __syncthreads();

    // scan 256 counters
    int cnt = hist[t];
    sdata[t] = cnt;
    __syncthreads();
    for (int o = 1; o < 256; o <<= 1) {
        int add = (t >= o) ? sdata[t - o] : 0;
        __syncthreads();
        sdata[t] += add;
        __syncthreads();
    }
    int excl = sdata[t] - cnt;
    lexcl[t] = excl;
    if (t == 255) lexcl[256] = sdata[255];
    hist[t] = excl;
    int gb = 0;
    if (t < NB && cnt > 0) gb = atomicAdd(&bucket_cursor[t], cnt);
    gbase[t] = t * CAP + gb;
    __syncthreads();

    // pass 2: rank + stage + fused global degree atomic
    #pragma unroll
    for (int j = 0; j < CHUNK / 256; ++j) {
        int i = base + t + j * 256;
        if (i < E) {
            int d = dbuf[t + j * 256];
            int s = srcp[i];
            int b = d >> BSH;
            int r = atomicAdd(&hist[b], 1);
            ebuf[r] = (s << BSH) | (d & 511);
            bkt[r] = (unsigned char)b;
            atomicAdd(&deg[d], 1);
        }
    }
    __syncthreads();

    // flush: dense per-bucket runs
    const int blockTotal = lexcl[256];
    for (int i = t; i < blockTotal; i += 256) {
        int b = bkt[i];
        eb[gbase[b] + (i - lexcl[b])] = ebuf[i];
    }
}

// ---------------------------------------------------------------------------
// K3a/b/c: exclusive scan of (deg+1) -> rowptr. +1 = analytic self-loop.
// ---------------------------------------------------------------------------
__global__ __launch_bounds__(256) void k_scan1(const int* __restrict__ deg,
                                               int* __restrict__ rowptr,
                                               int* __restrict__ bsum)
{
    __shared__ int sdata[256];
    const int b = blockIdx.x, t = threadIdx.x;
    const int base = b * 2048 + t * 8;
    int v[8];
    int sum = 0;
    #pragma unroll
    for (int j = 0; j < 8; ++j) {
        int idx = base + j;
        v[j] = (idx < N_NODES) ? (deg[idx] + 1) : 0;
        sum += v[j];
    }
    sdata[t] = sum;
    __syncthreads();
    for (int o = 1; o < 256; o <<= 1) {
        int add = (t >= o) ? sdata[t - o] : 0;
        __syncthreads();
        sdata[t] += add;
        __syncthreads();
    }
    int excl = sdata[t] - sum;
    if (t == 255) bsum[b] = sdata[255];
    int run = excl;
    #pragma unroll
    for (int j = 0; j < 8; ++j) {
        int idx = base + j;
        if (idx < N_NODES) rowptr[idx] = run;
        run += v[j];
    }
}

__global__ void k_scan2(int* __restrict__ bsum, int nb)
{
    int lane = threadIdx.x;
    int v = (lane < nb) ? bsum[lane] : 0;
    int incl = v;
    #pragma unroll
    for (int o = 1; o < 64; o <<= 1) {
        int x = __shfl_up(incl, o);
        if (lane >= o) incl += x;
    }
    if (lane < nb) bsum[lane] = incl - v;
}

__global__ __launch_bounds__(256) void k_scan3(int* __restrict__ rowptr,
                                               const int* __restrict__ bsum,
                                               int total)
{
    int i = blockIdx.x * 256 + threadIdx.x;
    if (i == 0) rowptr[N_NODES] = total;
    if (i < N_NODES) rowptr[i] += bsum[i >> 11];
}

// ---------------------------------------------------------------------------
// K4: single-pass CSR placement. One 512-thread block per bucket; cursors
// seeded from rowptr in LDS; self-loop written at slot 0 of each segment.
// ---------------------------------------------------------------------------
__global__ __launch_bounds__(512) void k_csr(const int* __restrict__ eb,
                                             const int* __restrict__ bucket_cursor,
                                             const int* __restrict__ rowptr,
                                             int* __restrict__ col)
{
    __shared__ int cur[512];
    const int t = threadIdx.x;
    const int b = blockIdx.x;
    const int n0 = b * 512;
    const int cnt = bucket_cursor[b];
    const int ebase = b * CAP;

    int n = n0 + t;
    if (n < N_NODES) {
        int rp = rowptr[n];
        col[rp] = n;              // self-loop first
        cur[t] = rp + 1;
    }
    __syncthreads();

    for (int i = t; i < cnt; i += 512) {
        int v = eb[ebase + i];
        int r = atomicAdd(&cur[v & 511], 1);
        col[r] = v >> BSH;
    }
}

// ---------------------------------------------------------------------------
// K5: per-dst-node softmax + aggregation. One wave per node; bf16 h gathers
// (256 B/edge), edge loop unrolled x8 for memory-level parallelism.
// ---------------------------------------------------------------------------
__global__ __launch_bounds__(256) void k_node(const unsigned short* __restrict__ hb,
                                              const float* __restrict__ a_src,
                                              const float* __restrict__ a_dst,
                                              const int* __restrict__ rowptr,
                                              const int* __restrict__ col,
                                              const float* __restrict__ bias,
                                              float* __restrict__ out)
{
    const int lane = threadIdx.x & 63;
    const int node = blockIdx.x * 4 + (threadIdx.x >> 6);
    if (node >= N_NODES) return;

    const int r0 = rowptr[node];
    const int r1 = rowptr[node + 1];
    const int myh = lane >> 4;
    const float adm = a_dst[node * NH + myh];

    float denom = 0.f, acc0 = 0.f, acc1 = 0.f;
    int i = r0;
    for (; i + 8 <= r1; i += 8) {
        int s[8];
        #pragma unroll
        for (int j = 0; j < 8; ++j) s[j] = col[i + j];
        float as[8];
        #pragma unroll
        for (int j = 0; j < 8; ++j) as[j] = a_src[s[j] * NH + myh];
        unsigned int hv[8];
        #pragma unroll
        for (int j = 0; j < 8; ++j)
            hv[j] = *(const unsigned int*)&hb[(size_t)s[j] * HC + 2 * lane];
        #pragma unroll
        for (int j = 0; j < 8; ++j) {
            float p = __expf(leaky(as[j] + adm));
            denom += p;
            acc0 += p * __uint_as_float(hv[j] << 16);
            acc1 += p * __uint_as_float(hv[j] & 0xffff0000u);
        }
    }
    for (; i < r1; ++i) {
        int s = col[i];
        float p = __expf(leaky(a_src[s * NH + myh] + adm));
        unsigned int v = *(const unsigned int*)&hb[(size_t)s * HC + 2 * lane];
        denom += p;
        acc0 += p * __uint_as_float(v << 16);
        acc1 += p * __uint_as_float(v & 0xffff0000u);
    }

    float inv = 1.f / (denom + 1e-16f);
    float2 o2;
    o2.x = acc0 * inv + bias[2 * lane];
    o2.y = acc1 * inv + bias[2 * lane + 1];
    *(float2*)&out[(size_t)node * HC + 2 * lane] = o2;
}

// ---------------------------------------------------------------------------
extern "C" void kernel_launch(void* const* d_in, const int* in_sizes, int n_in,
                              void* d_out, int out_size, void* d_ws, size_t ws_size,
                              hipStream_t stream)
{
    const float* x       = (const float*)d_in[0];
    const float* W       = (const float*)d_in[1];
    const float* att_src = (const float*)d_in[2];
    const float* att_dst = (const float*)d_in[3];
    const float* bias    = (const float*)d_in[4];
    const int*   ei      = (const int*)d_in[5];
    const int E = in_sizes[5] / 2;
    const int* srcp = ei;
    const int* dstp = ei + E;
    float* out = (float*)d_out;

    char* wsb = (char*)d_ws;
    size_t off = 0;
    auto alloc = [&](size_t bytes) -> char* {
        char* p = wsb + off;
        off += (bytes + 255) & ~(size_t)255;
        return p;
    };
    unsigned short* hb = (unsigned short*)alloc((size_t)N_NODES * HC * sizeof(unsigned short)); // 25.6 MB
    float* a_src   = (float*)alloc((size_t)N_NODES * NH * sizeof(float));
    float* a_dst   = (float*)alloc((size_t)N_NODES * NH * sizeof(float));
    int*   deg     = (int*)alloc((size_t)N_NODES * sizeof(int));
    int*   rowptr  = (int*)alloc((size_t)(N_NODES + 1) * sizeof(int));
    int*   bsum    = (int*)alloc(64 * sizeof(int));
    int*   eb      = (int*)alloc((size_t)NB * CAP * sizeof(int));          // 8.0 MB
    int*   col     = (int*)alloc((size_t)(E + N_NODES) * sizeof(int));     // 6.8 MB
    int*   bcursor = (int*)alloc(256 * sizeof(int));

    const int total = E + N_NODES;

    hipMemsetAsync(deg, 0, (size_t)N_NODES * sizeof(int), stream);
    hipMemsetAsync(bcursor, 0, 256 * sizeof(int), stream);

    k_gemm<<<(N_NODES + 63) / 64, 256, 0, stream>>>(x, W, att_src, att_dst,
                                                    hb, a_src, a_dst);
    k_bucket<<<(E + CHUNK - 1) / CHUNK, 256, 0, stream>>>(srcp, dstp, bcursor, deg, eb, E);
    k_scan1<<<49, 256, 0, stream>>>(deg, rowptr, bsum);
    k_scan2<<<1, 64, 0, stream>>>(bsum, 49);
    k_scan3<<<(N_NODES + 255) / 256, 256, 0, stream>>>(rowptr, bsum, total);
    k_csr<<<NB, 512, 0, stream>>>(eb, bcursor, rowptr, col);
    k_node<<<(N_NODES + 3) / 4, 256, 0, stream>>>(hb, a_src, a_dst, rowptr, col, bias, out);
}

// Round 6
// 294.939 us; speedup vs baseline: 1.1779x; 1.1779x over previous
//
#include <hip/hip_runtime.h>
#include <hip/hip_bf16.h>
#include <math.h>

#define N_NODES 100000
#define F_IN    128
#define HC      128      // H*C
#define NH      4
#define SLOPE   0.2f

#define NB      196      // buckets = ceil(N/512)
#define BSH     9        // bucket = dst >> 9, local = dst & 511
#define CAP     10240    // per-bucket arena capacity (mean 8163, sigma ~90)
#define CHUNK   8192     // edges per k_bucket block
#define PADK    136      // LDS row stride in shorts (128 + 8 pad)

typedef __attribute__((ext_vector_type(8))) short short8;   // bf16x8 MFMA frag
typedef __attribute__((ext_vector_type(4))) float f32x4;    // MFMA accum
typedef __attribute__((ext_vector_type(2))) float fx2;      // native float2 (NT store ok)

static __device__ __forceinline__ float leaky(float x) { return x > 0.f ? x : SLOPE * x; }

static __device__ __forceinline__ short f2bs(float f) {
    __hip_bfloat16 b = __float2bfloat16(f);   // RTN-even
    return *reinterpret_cast<short*>(&b);
}

// ---------------------------------------------------------------------------
// K1: h = x @ W via bf16 MFMA (fp32 accum). Block = 64 rows x 128 cols,
// 4 waves; wave w owns rows w*16..w*16+15; 8 n-tiles x 4 k-blocks of
// mfma_f32_16x16x32_bf16. x and W converted to bf16 during LDS staging.
// Epilogue: bf16 h store + fp32 a_src/a_dst (per-head dot + 4-step shfl tree).
// ---------------------------------------------------------------------------
__global__ __launch_bounds__(256) void k_gemm(const float* __restrict__ x,
                                              const float* __restrict__ W,
                                              const float* __restrict__ att_src,
                                              const float* __restrict__ att_dst,
                                              unsigned short* __restrict__ hb,
                                              float* __restrict__ a_src,
                                              float* __restrict__ a_dst)
{
    __shared__ short xs[64 * PADK];    // bf16 x tile [row][k]   17.4 KB
    __shared__ short ws[128 * PADK];   // bf16 W^T    [n][k]     34.8 KB
    const int t  = threadIdx.x;
    const int r0 = blockIdx.x * 64;

    // stage x tile (fp32 -> bf16): 64 rows x 32 float4 chunks
    for (int i = t; i < 2048; i += 256) {
        int row = i >> 5, kq = (i & 31) * 4;
        int gr = r0 + row;
        float4 v = make_float4(0.f, 0.f, 0.f, 0.f);
        if (gr < N_NODES) v = ((const float4*)(x + (size_t)gr * F_IN))[i & 31];
        short* p = &xs[row * PADK + kq];
        p[0] = f2bs(v.x); p[1] = f2bs(v.y); p[2] = f2bs(v.z); p[3] = f2bs(v.w);
    }
    // stage W^T (fp32 -> bf16): read W[k][n] coalesced, write ws[n][k]
    for (int i = t; i < 4096; i += 256) {
        int k = i >> 5, nq = (i & 31) * 4;
        float4 v = *(const float4*)&W[k * HC + nq];
        ws[(nq + 0) * PADK + k] = f2bs(v.x);
        ws[(nq + 1) * PADK + k] = f2bs(v.y);
        ws[(nq + 2) * PADK + k] = f2bs(v.z);
        ws[(nq + 3) * PADK + k] = f2bs(v.w);
    }
    __syncthreads();

    const int wave = t >> 6, lane = t & 63;
    const int quad = lane >> 4, l16 = lane & 15;
    const int wrow = wave * 16;

    f32x4 acc[8];
    #pragma unroll
    for (int nt = 0; nt < 8; ++nt) acc[nt] = (f32x4){0.f, 0.f, 0.f, 0.f};

    const short* ap = &xs[(wrow + l16) * PADK + quad * 8];
    #pragma unroll
    for (int kb = 0; kb < 4; ++kb) {
        short8 a = *(const short8*)(ap + kb * 32);
        #pragma unroll
        for (int nt = 0; nt < 8; ++nt) {
            short8 b = *(const short8*)&ws[(nt * 16 + l16) * PADK + kb * 32 + quad * 8];
            acc[nt] = __builtin_amdgcn_mfma_f32_16x16x32_bf16(a, b, acc[nt], 0, 0, 0);
        }
    }

    // att vectors for my column residue: col = nt*16 + l16
    float att_s[8], att_d[8];
    #pragma unroll
    for (int nt = 0; nt < 8; ++nt) {
        att_s[nt] = att_src[nt * 16 + l16];
        att_d[nt] = att_dst[nt * 16 + l16];
    }

    #pragma unroll
    for (int g = 0; g < 4; ++g) {
        int r = r0 + wrow + quad * 4 + g;
        // h store: D[row][col=nt*16+l16]
        if (r < N_NODES) {
            #pragma unroll
            for (int nt = 0; nt < 8; ++nt)
                hb[(size_t)r * HC + nt * 16 + l16] = (unsigned short)f2bs(acc[nt][g]);
        }
        // per-head partials (head = nt>>1)
        float s0 = acc[0][g] * att_s[0] + acc[1][g] * att_s[1];
        float s1 = acc[2][g] * att_s[2] + acc[3][g] * att_s[3];
        float s2 = acc[4][g] * att_s[4] + acc[5][g] * att_s[5];
        float s3 = acc[6][g] * att_s[6] + acc[7][g] * att_s[7];
        float d0 = acc[0][g] * att_d[0] + acc[1][g] * att_d[1];
        float d1 = acc[2][g] * att_d[2] + acc[3][g] * att_d[3];
        float d2 = acc[4][g] * att_d[4] + acc[5][g] * att_d[5];
        float d3 = acc[6][g] * att_d[6] + acc[7][g] * att_d[7];
        #pragma unroll
        for (int o = 1; o < 16; o <<= 1) {
            s0 += __shfl_xor(s0, o); s1 += __shfl_xor(s1, o);
            s2 += __shfl_xor(s2, o); s3 += __shfl_xor(s3, o);
            d0 += __shfl_xor(d0, o); d1 += __shfl_xor(d1, o);
            d2 += __shfl_xor(d2, o); d3 += __shfl_xor(d3, o);
        }
        if (l16 == 0 && r < N_NODES) {
            *(float4*)&a_src[r * NH] = make_float4(s0, s1, s2, s3);
            *(float4*)&a_dst[r * NH] = make_float4(d0, d1, d2, d3);
        }
    }
}

// ---------------------------------------------------------------------------
// K2: multisplit edges into NB dst-buckets via LDS staging; dense flushes.
// eb[bucket*CAP + k] = (src<<9) | (dst&511). Self-loops never bucketed.
// ---------------------------------------------------------------------------
__global__ __launch_bounds__(256) void k_bucket(const int* __restrict__ srcp,
                                                const int* __restrict__ dstp,
                                                int* __restrict__ bucket_cursor,
                                                int* __restrict__ eb, int E)
{
    __shared__ int ebuf[CHUNK];
    __shared__ unsigned char bkt[CHUNK];
    __shared__ int hist[256];
    __shared__ int lexcl[257];
    __shared__ int gbase[256];
    __shared__ int sdata[256];

    const int t = threadIdx.x;
    const int base = blockIdx.x * CHUNK;

    hist[t] = 0;
    __syncthreads();

    #pragma unroll
    for (int j = 0; j < CHUNK / 256; ++j) {
        int i = base + t + j * 256;
        if (i < E) atomicAdd(&hist[dstp[i] >> BSH], 1);
    }
    __syncthreads();

    int cnt = hist[t];
    sdata[t] = cnt;
    __syncthreads();
    for (int o = 1; o < 256; o <<= 1) {
        int add = (t >= o) ? sdata[t - o] : 0;
        __syncthreads();
        sdata[t] += add;
        __syncthreads();
    }
    int excl = sdata[t] - cnt;
    lexcl[t] = excl;
    if (t == 255) lexcl[256] = sdata[255];
    hist[t] = excl;
    int gb = 0;
    if (t < NB && cnt > 0) gb = atomicAdd(&bucket_cursor[t], cnt);
    gbase[t] = t * CAP + gb;
    __syncthreads();

    #pragma unroll
    for (int j = 0; j < CHUNK / 256; ++j) {
        int i = base + t + j * 256;
        if (i < E) {
            int s = srcp[i], d = dstp[i];
            int b = d >> BSH;
            int r = atomicAdd(&hist[b], 1);
            ebuf[r] = (s << BSH) | (d & 511);
            bkt[r] = (unsigned char)b;
        }
    }
    __syncthreads();

    const int blockTotal = lexcl[256];
    for (int i = t; i < blockTotal; i += 256) {
        int b = bkt[i];
        eb[gbase[b] + (i - lexcl[b])] = ebuf[i];
    }
}

// ---------------------------------------------------------------------------
// K3: exclusive scan of bucket counts (+ self-loops) -> bexcl
// ---------------------------------------------------------------------------
__global__ void k_bscan(const int* __restrict__ bucket_cursor,
                        int* __restrict__ bexcl)
{
    __shared__ int sdata[256];
    const int t = threadIdx.x;
    int nvalid = 0;
    if (t < NB) {
        int n0 = t * 512;
        nvalid = min(512, N_NODES - n0);
        if (nvalid < 0) nvalid = 0;
    }
    int v = (t < NB) ? bucket_cursor[t] + nvalid : 0;
    sdata[t] = v;
    __syncthreads();
    for (int o = 1; o < 256; o <<= 1) {
        int add = (t >= o) ? sdata[t - o] : 0;
        __syncthreads();
        sdata[t] += add;
        __syncthreads();
    }
    if (t < NB) bexcl[t] = sdata[t] - v;
}

// ---------------------------------------------------------------------------
// K4: per-bucket CSR build. LDS histogram + scan; self-loop at slot 0.
// ---------------------------------------------------------------------------
__global__ __launch_bounds__(256) void k_csr(const int* __restrict__ eb,
                                             const int* __restrict__ bucket_cursor,
                                             const int* __restrict__ bexcl,
                                             int* __restrict__ col,
                                             int2* __restrict__ rowse)
{
    __shared__ int deg[512];
    __shared__ int sdata[256];

    const int t  = threadIdx.x;
    const int b  = blockIdx.x;
    const int n0 = b * 512;
    const int cnt   = bucket_cursor[b];
    const int ebase = b * CAP;
    const int gofs  = bexcl[b];

    deg[t]       = (n0 + t       < N_NODES) ? 1 : 0;
    deg[t + 256] = (n0 + t + 256 < N_NODES) ? 1 : 0;
    __syncthreads();

    for (int i = t; i < cnt; i += 256)
        atomicAdd(&deg[eb[ebase + i] & 511], 1);
    __syncthreads();

    int d0 = deg[2 * t], d1 = deg[2 * t + 1];
    int ps = d0 + d1;
    sdata[t] = ps;
    __syncthreads();
    for (int o = 1; o < 256; o <<= 1) {
        int add = (t >= o) ? sdata[t - o] : 0;
        __syncthreads();
        sdata[t] += add;
        __syncthreads();
    }
    int e0 = sdata[t] - ps;
    int e1 = e0 + d0;
    __syncthreads();

    int na = n0 + 2 * t, nb2 = n0 + 2 * t + 1;
    if (na < N_NODES) {
        rowse[na] = make_int2(gofs + e0, gofs + e0 + d0);
        col[gofs + e0] = na;
    }
    if (nb2 < N_NODES) {
        rowse[nb2] = make_int2(gofs + e1, gofs + e1 + d1);
        col[gofs + e1] = nb2;
    }
    deg[2 * t]     = e0 + 1;
    deg[2 * t + 1] = e1 + 1;
    __syncthreads();

    for (int i = t; i < cnt; i += 256) {
        int v = eb[ebase + i];
        int r = atomicAdd(&deg[v & 511], 1);
        col[gofs + r] = v >> BSH;
    }
}

// ---------------------------------------------------------------------------
// K5: per-dst-node softmax + aggregation. One wave per node; bf16 h gathers,
// x8 unroll; non-temporal out stores (keep L2/L3 for the hb gather set).
// ---------------------------------------------------------------------------
__global__ __launch_bounds__(256) void k_node(const unsigned short* __restrict__ hb,
                                              const float* __restrict__ a_src,
                                              const float* __restrict__ a_dst,
                                              const int2* __restrict__ rowse,
                                              const int* __restrict__ col,
                                              const float* __restrict__ bias,
                                              float* __restrict__ out)
{
    const int lane = threadIdx.x & 63;
    const int node = blockIdx.x * 4 + (threadIdx.x >> 6);
    if (node >= N_NODES) return;

    const int2 se = rowse[node];
    const int r0 = se.x, r1 = se.y;
    const int myh = lane >> 4;
    const float adm = a_dst[node * NH + myh];

    float denom = 0.f, acc0 = 0.f, acc1 = 0.f;
    int i = r0;
    for (; i + 8 <= r1; i += 8) {
        int s[8];
        #pragma unroll
        for (int j = 0; j < 8; ++j) s[j] = col[i + j];
        float as[8];
        #pragma unroll
        for (int j = 0; j < 8; ++j) as[j] = a_src[s[j] * NH + myh];
        unsigned int hv[8];
        #pragma unroll
        for (int j = 0; j < 8; ++j)
            hv[j] = *(const unsigned int*)&hb[(size_t)s[j] * HC + 2 * lane];
        #pragma unroll
        for (int j = 0; j < 8; ++j) {
            float p = __expf(leaky(as[j] + adm));
            denom += p;
            acc0 += p * __uint_as_float(hv[j] << 16);
            acc1 += p * __uint_as_float(hv[j] & 0xffff0000u);
        }
    }
    for (; i < r1; ++i) {
        int s = col[i];
        float p = __expf(leaky(a_src[s * NH + myh] + adm));
        unsigned int v = *(const unsigned int*)&hb[(size_t)s * HC + 2 * lane];
        denom += p;
        acc0 += p * __uint_as_float(v << 16);
        acc1 += p * __uint_as_float(v & 0xffff0000u);
    }

    float inv = 1.f / (denom + 1e-16f);
    fx2 o2;
    o2.x = acc0 * inv + bias[2 * lane];
    o2.y = acc1 * inv + bias[2 * lane + 1];
    __builtin_nontemporal_store(o2, (fx2*)&out[(size_t)node * HC + 2 * lane]);
}

// ---------------------------------------------------------------------------
extern "C" void kernel_launch(void* const* d_in, const int* in_sizes, int n_in,
                              void* d_out, int out_size, void* d_ws, size_t ws_size,
                              hipStream_t stream)
{
    const float* x       = (const float*)d_in[0];
    const float* W       = (const float*)d_in[1];
    const float* att_src = (const float*)d_in[2];
    const float* att_dst = (const float*)d_in[3];
    const float* bias    = (const float*)d_in[4];
    const int*   ei      = (const int*)d_in[5];
    const int E = in_sizes[5] / 2;
    const int* srcp = ei;
    const int* dstp = ei + E;
    float* out = (float*)d_out;

    char* wsb = (char*)d_ws;
    size_t off = 0;
    auto alloc = [&](size_t bytes) -> char* {
        char* p = wsb + off;
        off += (bytes + 255) & ~(size_t)255;
        return p;
    };
    unsigned short* hb = (unsigned short*)alloc((size_t)N_NODES * HC * sizeof(unsigned short)); // 25.6 MB
    float* a_src   = (float*)alloc((size_t)N_NODES * NH * sizeof(float));
    float* a_dst   = (float*)alloc((size_t)N_NODES * NH * sizeof(float));
    int*   eb      = (int*)alloc((size_t)NB * CAP * sizeof(int));          // 8.0 MB
    int*   col     = (int*)alloc((size_t)(E + N_NODES) * sizeof(int));     // 6.8 MB
    int2*  rowse   = (int2*)alloc((size_t)N_NODES * sizeof(int2));         // 0.8 MB
    int*   bcursor = (int*)alloc(256 * sizeof(int));
    int*   bexcl   = (int*)alloc(256 * sizeof(int));

    (void)hipMemsetAsync(bcursor, 0, 256 * sizeof(int), stream);

    k_gemm<<<(N_NODES + 63) / 64, 256, 0, stream>>>(x, W, att_src, att_dst,
                                                    hb, a_src, a_dst);
    k_bucket<<<(E + CHUNK - 1) / CHUNK, 256, 0, stream>>>(srcp, dstp, bcursor, eb, E);
    k_bscan<<<1, 256, 0, stream>>>(bcursor, bexcl);
    k_csr<<<NB, 256, 0, stream>>>(eb, bcursor, bexcl, col, rowse);
    k_node<<<(N_NODES + 3) / 4, 256, 0, stream>>>(hb, a_src, a_dst, rowse, col, bias, out);
}